// Round 1
// baseline (1871.952 us; speedup 1.0000x reference)
//
#include <hip/hip_runtime.h>
#include <hip/hip_bf16.h>

#define NN 100000
#define NE 50000
#define NT 2000
#define DD 128
#define NEDGE 1600000
#define HID 512
#define OUTD 128
#define K1 (3*DD)   // 384

typedef __bf16 bf16x8 __attribute__((ext_vector_type(8)));
typedef float  f32x4  __attribute__((ext_vector_type(4)));

__device__ __forceinline__ __bf16 f2b(float f) {
    __hip_bfloat16 h = __float2bfloat16(f);
    union { __hip_bfloat16 h; __bf16 b; } u; u.h = h; return u.b;
}

// ---- edge aggregation: acc[row] += feats[col], deg[row] += 1 ----
__global__ void edge_agg(const float* __restrict__ feats,
                         const int* __restrict__ row,
                         const int* __restrict__ col,
                         int n_edges,
                         float* __restrict__ acc,
                         float* __restrict__ deg) {
    int e = blockIdx.x * 2 + (threadIdx.x >> 7);
    int d = threadIdx.x & 127;
    if (e >= n_edges) return;
    int r = row[e];
    int c = col[e];
    atomicAdd(&acc[r * DD + d], feats[c * DD + d]);
    if (d == 0) atomicAdd(&deg[r], 1.0f);
}

// ---- W1 [384,512] -> W1T bf16 [512,384]; W2 [512,128] -> W2T bf16 [128,512] ----
__global__ void conv_w(const float* __restrict__ W1, const float* __restrict__ W2,
                       __bf16* __restrict__ W1T, __bf16* __restrict__ W2T) {
    int i = blockIdx.x * 256 + threadIdx.x;
    if (i < K1 * HID) {
        int k = i / HID, n = i % HID;
        W1T[n * K1 + k] = f2b(W1[i]);
    } else {
        int j = i - K1 * HID;
        if (j < HID * OUTD) {
            int k = j / OUTD, n = j % OUTD;
            W2T[n * HID + k] = f2b(W2[j]);
        }
    }
}

// ---- X[n] = concat(news[n], ent_acc[n]/deg_e, top_acc[n]/deg_t) in bf16 ----
__global__ void build_x(const float* __restrict__ news,
                        const float* __restrict__ ent_acc,
                        const float* __restrict__ top_acc,
                        const float* __restrict__ deg_e,
                        const float* __restrict__ deg_t,
                        __bf16* __restrict__ X) {
    int i = blockIdx.x * 256 + threadIdx.x;
    if (i >= NN * DD) return;
    int node = i >> 7;
    int d = i & 127;
    float ie = 1.0f / (deg_e[node] + 1e-8f);
    float it = 1.0f / (deg_t[node] + 1e-8f);
    __bf16* xr = X + node * K1;
    xr[d]          = f2b(news[i]);
    xr[DD + d]     = f2b(ent_acc[i] * ie);
    xr[2*DD + d]   = f2b(top_acc[i] * it);
}

// ---- C[M,N] = act(A[M,K] @ BT[N,K]^T + bias), bf16 MFMA 16x16x32 ----
// 64x64 tile, BK=32, 256 threads = 4 waves; wave w covers m-rows [w*16,w*16+16),
// 4 n-subtiles of 16. LDS in quad-major [q][row][8] layout -> conflict-free
// 16B fragment reads.
template<int TANH>
__global__ __launch_bounds__(256) void gemm_bt(const __bf16* __restrict__ A,
                                               const __bf16* __restrict__ BT,
                                               const float* __restrict__ bias,
                                               void* __restrict__ Cout,
                                               int M, int N, int K) {
    __shared__ __bf16 As[4 * 64 * 8];
    __shared__ __bf16 Bs[4 * 64 * 8];
    const int bm = blockIdx.x * 64;
    const int bn = blockIdx.y * 64;
    const int t = threadIdx.x;
    const int lane = t & 63;
    const int w = t >> 6;
    const int quad = lane >> 4;
    const int l16 = lane & 15;

    // staging assignment: thread t loads 8 contiguous bf16 of row (t>>2), k-quad (t&3)
    const int srow = t >> 2;
    const int sq = t & 3;
    const __bf16* Aptr = A + (long)(bm + srow) * K + sq * 8;
    const __bf16* Bptr = BT + (long)(bn + srow) * K + sq * 8;
    const bool arow_ok = (bm + srow) < M;

    f32x4 acc[4];
    #pragma unroll
    for (int i = 0; i < 4; i++)
        #pragma unroll
        for (int j = 0; j < 4; j++) acc[i][j] = 0.0f;

    union { uint4 u; bf16x8 v; } zero; zero.u = make_uint4(0,0,0,0);

    const int nk = K / 32;
    for (int kt = 0; kt < nk; kt++) {
        bf16x8 av = zero.v;
        if (arow_ok) av = *(const bf16x8*)(Aptr + kt * 32);
        bf16x8 bv = *(const bf16x8*)(Bptr + kt * 32);
        __syncthreads();
        *(bf16x8*)&As[sq * 512 + srow * 8] = av;
        *(bf16x8*)&Bs[sq * 512 + srow * 8] = bv;
        __syncthreads();
        bf16x8 a = *(const bf16x8*)&As[quad * 512 + (w * 16 + l16) * 8];
        #pragma unroll
        for (int tt = 0; tt < 4; tt++) {
            bf16x8 b = *(const bf16x8*)&Bs[quad * 512 + (tt * 16 + l16) * 8];
            acc[tt] = __builtin_amdgcn_mfma_f32_16x16x32_bf16(a, b, acc[tt], 0, 0, 0);
        }
    }

    // epilogue: C/D layout col=lane&15, row=quad*4+reg
    const int rbase = bm + w * 16 + quad * 4;
    #pragma unroll
    for (int tt = 0; tt < 4; tt++) {
        int gc = bn + tt * 16 + l16;
        float bb = bias[gc];
        #pragma unroll
        for (int r = 0; r < 4; r++) {
            int gr = rbase + r;
            if (gr < M) {
                float v = acc[tt][r] + bb;
                if (TANH) {
                    ((__bf16*)Cout)[(long)gr * N + gc] = f2b(tanhf(v));
                } else {
                    ((float*)Cout)[(long)gr * N + gc] = v;
                }
            }
        }
    }
}

extern "C" void kernel_launch(void* const* d_in, const int* in_sizes, int n_in,
                              void* d_out, int out_size, void* d_ws, size_t ws_size,
                              hipStream_t stream) {
    const float* news  = (const float*)d_in[0];
    const float* ent_f = (const float*)d_in[1];
    const float* top_f = (const float*)d_in[2];
    const int* ent_row = (const int*)d_in[3];
    const int* ent_col = (const int*)d_in[4];
    const int* top_row = (const int*)d_in[5];
    const int* top_col = (const int*)d_in[6];
    const float* W1 = (const float*)d_in[7];
    const float* b1 = (const float*)d_in[8];
    const float* W2 = (const float*)d_in[9];
    const float* b2 = (const float*)d_in[10];

    char* ws = (char*)d_ws;
    // layout (bytes):
    //   [0,            51,200,000)  ent_acc f32 [100000*128]   (aliased later by H)
    //   [51,200,000,  102,400,000)  top_acc f32
    //   [102,400,000, 102,800,000)  deg_e f32 [100000]
    //   [102,800,000, 103,200,000)  deg_t f32
    //   [103,200,000, 180,000,000)  X bf16 [100000*384]
    //   [180,000,000, 180,393,216)  W1T bf16 [512*384]
    //   [180,400,000, 180,531,072)  W2T bf16 [128*512]
    float* ent_acc = (float*)(ws + 0);
    float* top_acc = (float*)(ws + 51200000);
    float* deg_e   = (float*)(ws + 102400000);
    float* deg_t   = (float*)(ws + 102800000);
    __bf16* X      = (__bf16*)(ws + 103200000);
    __bf16* W1T    = (__bf16*)(ws + 180000000);
    __bf16* W2T    = (__bf16*)(ws + 180400000);
    __bf16* H      = (__bf16*)(ws + 0);   // reuses ent_acc+top_acc (102.4MB) after build_x

    hipMemsetAsync(ws, 0, 103200000, stream);
    conv_w<<<1024, 256, 0, stream>>>(W1, W2, W1T, W2T);
    edge_agg<<<NEDGE / 2, 256, 0, stream>>>(ent_f, ent_row, ent_col, NEDGE, ent_acc, deg_e);
    edge_agg<<<NEDGE / 2, 256, 0, stream>>>(top_f, top_row, top_col, NEDGE, top_acc, deg_t);
    build_x<<<(NN * DD) / 256, 256, 0, stream>>>(news, ent_acc, top_acc, deg_e, deg_t, X);
    gemm_bt<1><<<dim3(1563, 8), 256, 0, stream>>>(X, W1T, b1, (void*)H, NN, HID, K1);
    gemm_bt<0><<<dim3(1563, 2), 256, 0, stream>>>(H, W2T, b2, d_out, NN, OUTD, HID);
}

// Round 2
// 1004.069 us; speedup vs baseline: 1.8644x; 1.8644x over previous
//
#include <hip/hip_runtime.h>
#include <hip/hip_bf16.h>

#define NN 100000
#define NE 50000
#define NT 2000
#define DD 128
#define NEDGE 1600000
#define HID 512
#define OUTD 128
#define K1 (3*DD)   // 384
#define NSCAN (NN+1)          // 100001
#define SCAN_BLOCKS 391       // ceil(100001/256)

typedef __bf16 bf16x8 __attribute__((ext_vector_type(8)));
typedef __bf16 bf16x2 __attribute__((ext_vector_type(2)));
typedef float  f32x4  __attribute__((ext_vector_type(4)));

__device__ __forceinline__ __bf16 f2b(float f) {
    __hip_bfloat16 h = __float2bfloat16(f);
    union { __hip_bfloat16 h; __bf16 b; } u; u.h = h; return u.b;
}

// ---- pass 1: count edges per news node (counts stored at offs[row+1]) ----
__global__ void count_edges(const int* __restrict__ er, const int* __restrict__ tr,
                            int* __restrict__ offs_e, int* __restrict__ offs_t) {
    int e = blockIdx.x * 256 + threadIdx.x;
    if (e >= NEDGE) return;
    atomicAdd(&offs_e[er[e] + 1], 1);
    atomicAdd(&offs_t[tr[e] + 1], 1);
}

// ---- hierarchical inclusive scan over offs arrays (length NSCAN) ----
__global__ void scan1(int* __restrict__ offs_e, int* __restrict__ offs_t,
                      int* __restrict__ bsum_e, int* __restrict__ bsum_t) {
    int* offs = blockIdx.y ? offs_t : offs_e;
    int* bsum = blockIdx.y ? bsum_t : bsum_e;
    __shared__ int s[256];
    int i = blockIdx.x * 256 + threadIdx.x;
    int x = (i < NSCAN) ? offs[i] : 0;
    s[threadIdx.x] = x;
    __syncthreads();
    #pragma unroll
    for (int off = 1; off < 256; off <<= 1) {
        int v = (threadIdx.x >= off) ? s[threadIdx.x - off] : 0;
        __syncthreads();
        s[threadIdx.x] += v;
        __syncthreads();
    }
    if (i < NSCAN) offs[i] = s[threadIdx.x];
    if (threadIdx.x == 255) bsum[blockIdx.x] = s[255];
}

__global__ void scan2(int* __restrict__ bsum_e, int* __restrict__ bsum_t) {
    int* bsum = blockIdx.y ? bsum_t : bsum_e;
    __shared__ int s[512];
    int i = threadIdx.x;
    s[i] = (i < SCAN_BLOCKS) ? bsum[i] : 0;
    __syncthreads();
    #pragma unroll
    for (int off = 1; off < 512; off <<= 1) {
        int v = (i >= off) ? s[i - off] : 0;
        __syncthreads();
        s[i] += v;
        __syncthreads();
    }
    if (i < SCAN_BLOCKS) bsum[i] = s[i];
}

__global__ void scan3(int* __restrict__ offs_e, int* __restrict__ offs_t,
                      const int* __restrict__ bsum_e, const int* __restrict__ bsum_t,
                      int* __restrict__ cur_e, int* __restrict__ cur_t) {
    int* offs = blockIdx.y ? offs_t : offs_e;
    const int* bsum = blockIdx.y ? bsum_t : bsum_e;
    int* cur = blockIdx.y ? cur_t : cur_e;
    int i = blockIdx.x * 256 + threadIdx.x;
    if (i >= NSCAN) return;
    int v = offs[i] + (blockIdx.x ? bsum[blockIdx.x - 1] : 0);
    offs[i] = v;
    if (i < NN) cur[i] = v;
}

// ---- pass 2: scatter col indices into CSR slots ----
__global__ void scatter_edges(const int* __restrict__ er, const int* __restrict__ ec,
                              const int* __restrict__ tr, const int* __restrict__ tc,
                              int* __restrict__ cur_e, int* __restrict__ cur_t,
                              int* __restrict__ se, int* __restrict__ st) {
    int e = blockIdx.x * 256 + threadIdx.x;
    if (e >= NEDGE) return;
    int p = atomicAdd(&cur_e[er[e]], 1);
    se[p] = ec[e];
    int q = atomicAdd(&cur_t[tr[e]], 1);
    st[q] = tc[e];
}

// ---- gather-aggregate + fused X build. One wave per node; lane owns 2 dims ----
__global__ __launch_bounds__(256) void aggregate(const float* __restrict__ news,
                                                 const float* __restrict__ entf,
                                                 const float* __restrict__ topf,
                                                 const int* __restrict__ offs_e,
                                                 const int* __restrict__ offs_t,
                                                 const int* __restrict__ se,
                                                 const int* __restrict__ st,
                                                 __bf16* __restrict__ X) {
    int wave = threadIdx.x >> 6;
    int lane = threadIdx.x & 63;
    int node = blockIdx.x * 4 + wave;
    if (node >= NN) return;
    int d = lane * 2;
    float ax = 0.f, ay = 0.f, bx = 0.f, by = 0.f;
    int s0 = offs_e[node], s1 = offs_e[node + 1];
    for (int i = s0; i < s1; i++) {
        int c = se[i];
        const float2 v = *(const float2*)(entf + (long)c * DD + d);
        ax += v.x; ay += v.y;
    }
    int t0 = offs_t[node], t1 = offs_t[node + 1];
    for (int i = t0; i < t1; i++) {
        int c = st[i];
        const float2 v = *(const float2*)(topf + (long)c * DD + d);
        bx += v.x; by += v.y;
    }
    float ie = 1.0f / ((float)(s1 - s0) + 1e-8f);
    float it = 1.0f / ((float)(t1 - t0) + 1e-8f);
    const float2 nv = *(const float2*)(news + (long)node * DD + d);
    __bf16* xr = X + (long)node * K1;
    *(bf16x2*)(xr + d)          = bf16x2{f2b(nv.x),     f2b(nv.y)};
    *(bf16x2*)(xr + DD + d)     = bf16x2{f2b(ax * ie),  f2b(ay * ie)};
    *(bf16x2*)(xr + 2*DD + d)   = bf16x2{f2b(bx * it),  f2b(by * it)};
}

// ---- W1 [384,512] -> W1T bf16 [512,384]; W2 [512,128] -> W2T bf16 [128,512] ----
__global__ void conv_w(const float* __restrict__ W1, const float* __restrict__ W2,
                       __bf16* __restrict__ W1T, __bf16* __restrict__ W2T) {
    int i = blockIdx.x * 256 + threadIdx.x;
    if (i < K1 * HID) {
        int k = i / HID, n = i % HID;
        W1T[n * K1 + k] = f2b(W1[i]);
    } else {
        int j = i - K1 * HID;
        if (j < HID * OUTD) {
            int k = j / OUTD, n = j % OUTD;
            W2T[n * HID + k] = f2b(W2[j]);
        }
    }
}

// ---- C[M,N] = act(A[M,K] @ BT[N,K]^T + bias), bf16 MFMA 16x16x32 ----
template<int TANH>
__global__ __launch_bounds__(256) void gemm_bt(const __bf16* __restrict__ A,
                                               const __bf16* __restrict__ BT,
                                               const float* __restrict__ bias,
                                               void* __restrict__ Cout,
                                               int M, int N, int K) {
    __shared__ __bf16 As[4 * 64 * 8];
    __shared__ __bf16 Bs[4 * 64 * 8];
    const int bm = blockIdx.x * 64;
    const int bn = blockIdx.y * 64;
    const int t = threadIdx.x;
    const int lane = t & 63;
    const int w = t >> 6;
    const int quad = lane >> 4;
    const int l16 = lane & 15;

    const int srow = t >> 2;
    const int sq = t & 3;
    const __bf16* Aptr = A + (long)(bm + srow) * K + sq * 8;
    const __bf16* Bptr = BT + (long)(bn + srow) * K + sq * 8;
    const bool arow_ok = (bm + srow) < M;

    f32x4 acc[4];
    #pragma unroll
    for (int i = 0; i < 4; i++)
        #pragma unroll
        for (int j = 0; j < 4; j++) acc[i][j] = 0.0f;

    union { uint4 u; bf16x8 v; } zero; zero.u = make_uint4(0,0,0,0);

    const int nk = K / 32;
    for (int kt = 0; kt < nk; kt++) {
        bf16x8 av = zero.v;
        if (arow_ok) av = *(const bf16x8*)(Aptr + kt * 32);
        bf16x8 bv = *(const bf16x8*)(Bptr + kt * 32);
        __syncthreads();
        *(bf16x8*)&As[sq * 512 + srow * 8] = av;
        *(bf16x8*)&Bs[sq * 512 + srow * 8] = bv;
        __syncthreads();
        bf16x8 a = *(const bf16x8*)&As[quad * 512 + (w * 16 + l16) * 8];
        #pragma unroll
        for (int tt = 0; tt < 4; tt++) {
            bf16x8 b = *(const bf16x8*)&Bs[quad * 512 + (tt * 16 + l16) * 8];
            acc[tt] = __builtin_amdgcn_mfma_f32_16x16x32_bf16(a, b, acc[tt], 0, 0, 0);
        }
    }

    const int rbase = bm + w * 16 + quad * 4;
    #pragma unroll
    for (int tt = 0; tt < 4; tt++) {
        int gc = bn + tt * 16 + l16;
        float bb = bias[gc];
        #pragma unroll
        for (int r = 0; r < 4; r++) {
            int gr = rbase + r;
            if (gr < M) {
                float v = acc[tt][r] + bb;
                if (TANH) {
                    ((__bf16*)Cout)[(long)gr * N + gc] = f2b(tanhf(v));
                } else {
                    ((float*)Cout)[(long)gr * N + gc] = v;
                }
            }
        }
    }
}

extern "C" void kernel_launch(void* const* d_in, const int* in_sizes, int n_in,
                              void* d_out, int out_size, void* d_ws, size_t ws_size,
                              hipStream_t stream) {
    const float* news  = (const float*)d_in[0];
    const float* ent_f = (const float*)d_in[1];
    const float* top_f = (const float*)d_in[2];
    const int* ent_row = (const int*)d_in[3];
    const int* ent_col = (const int*)d_in[4];
    const int* top_row = (const int*)d_in[5];
    const int* top_col = (const int*)d_in[6];
    const float* W1 = (const float*)d_in[7];
    const float* b1 = (const float*)d_in[8];
    const float* W2 = (const float*)d_in[9];
    const float* b2 = (const float*)d_in[10];

    char* ws = (char*)d_ws;
    // layout (bytes):
    //   sort region (dead after `aggregate`; aliased by H):
    //     [0,         400016)   offs_e int[100001]
    //     [400016,    800032)   offs_t int[100001]
    //     [800032,   1200032)   cur_e  int[100000]
    //     [1200032,  1600032)   cur_t  int[100000]
    //     [1600032,  1602080)   bsum_e int[512]
    //     [1602080,  1604128)   bsum_t int[512]
    //     [1604160,  8004160)   se     int[1.6M]
    //     [8004160, 14404160)   st     int[1.6M]
    //   [0,         102400000)  H bf16 [100000*512]  (aliases sort region)
    //   [102400000, 179200000)  X bf16 [100000*384]
    //   [179200000, 179593216)  W1T bf16 [512*384]
    //   [179593216, 179724288)  W2T bf16 [128*512]
    int* offs_e = (int*)(ws + 0);
    int* offs_t = (int*)(ws + 400016);
    int* cur_e  = (int*)(ws + 800032);
    int* cur_t  = (int*)(ws + 1200032);
    int* bsum_e = (int*)(ws + 1600032);
    int* bsum_t = (int*)(ws + 1602080);
    int* se     = (int*)(ws + 1604160);
    int* st     = (int*)(ws + 8004160);
    __bf16* H   = (__bf16*)(ws + 0);
    __bf16* X   = (__bf16*)(ws + 102400000);
    __bf16* W1T = (__bf16*)(ws + 179200000);
    __bf16* W2T = (__bf16*)(ws + 179593216);

    hipMemsetAsync(ws, 0, 800032, stream);   // zero offs_e/offs_t only
    conv_w<<<1024, 256, 0, stream>>>(W1, W2, W1T, W2T);
    count_edges<<<NEDGE / 256, 256, 0, stream>>>(ent_row, top_row, offs_e, offs_t);
    scan1<<<dim3(SCAN_BLOCKS, 2), 256, 0, stream>>>(offs_e, offs_t, bsum_e, bsum_t);
    scan2<<<dim3(1, 2), 512, 0, stream>>>(bsum_e, bsum_t);
    scan3<<<dim3(SCAN_BLOCKS, 2), 256, 0, stream>>>(offs_e, offs_t, bsum_e, bsum_t, cur_e, cur_t);
    scatter_edges<<<NEDGE / 256, 256, 0, stream>>>(ent_row, ent_col, top_row, top_col,
                                                   cur_e, cur_t, se, st);
    aggregate<<<NN / 4, 256, 0, stream>>>(news, ent_f, top_f, offs_e, offs_t, se, st, X);
    gemm_bt<1><<<dim3(1563, 8), 256, 0, stream>>>(X, W1T, b1, (void*)H, NN, HID, K1);
    gemm_bt<0><<<dim3(1563, 2), 256, 0, stream>>>(H, W2T, b2, d_out, NN, OUTD, HID);
}

// Round 3
// 866.106 us; speedup vs baseline: 2.1613x; 1.1593x over previous
//
#include <hip/hip_runtime.h>
#include <hip/hip_bf16.h>

#define NN 100000
#define NE 50000
#define NT 2000
#define DD 128
#define NEDGE 1600000
#define HID 512
#define OUTD 128
#define K1 (3*DD)   // 384
#define NSCAN (NN+1)          // 100001
#define SCAN_BLOCKS 391       // ceil(100001/256)

typedef __bf16 bf16x8 __attribute__((ext_vector_type(8)));
typedef __bf16 bf16x4 __attribute__((ext_vector_type(4)));
typedef __bf16 bf16x2 __attribute__((ext_vector_type(2)));
typedef float  f32x4  __attribute__((ext_vector_type(4)));

__device__ __forceinline__ __bf16 f2b(float f) {
    __hip_bfloat16 h = __float2bfloat16(f);
    union { __hip_bfloat16 h; __bf16 b; } u; u.h = h; return u.b;
}

// async global->LDS, 16B per lane; lds base must be wave-uniform
__device__ __forceinline__ void gll16(const void* g, void* l) {
    __builtin_amdgcn_global_load_lds((const __attribute__((address_space(1))) void*)g,
                                     (__attribute__((address_space(3))) void*)l, 16, 0, 0);
}

__device__ __forceinline__ float ftanh(float x) {
    x = fminf(fmaxf(x, -15.f), 15.f);
    float t = __expf(2.f * x);
    return (t - 1.f) / (t + 1.f);
}

// ---- convert feature tables to bf16 ----
__global__ void conv_feats(const float* __restrict__ entf, const float* __restrict__ topf,
                           __bf16* __restrict__ entb, __bf16* __restrict__ topb) {
    long i = ((long)blockIdx.x * 256 + threadIdx.x) * 4;
    const long NEL = (long)NE * DD;   // 6.4M
    if (i < NEL) {
        float4 v = *(const float4*)(entf + i);
        *(bf16x4*)(entb + i) = bf16x4{f2b(v.x), f2b(v.y), f2b(v.z), f2b(v.w)};
    } else {
        long j = i - NEL;
        float4 v = *(const float4*)(topf + j);
        *(bf16x4*)(topb + j) = bf16x4{f2b(v.x), f2b(v.y), f2b(v.z), f2b(v.w)};
    }
}

// ---- pass 1: count edges per news node (counts stored at offs[row+1]) ----
__global__ void count_edges(const int* __restrict__ er, const int* __restrict__ tr,
                            int* __restrict__ offs_e, int* __restrict__ offs_t) {
    int e = blockIdx.x * 256 + threadIdx.x;
    if (e >= NEDGE) return;
    atomicAdd(&offs_e[er[e] + 1], 1);
    atomicAdd(&offs_t[tr[e] + 1], 1);
}

// ---- hierarchical inclusive scan over offs arrays (length NSCAN) ----
__global__ void scan1(int* __restrict__ offs_e, int* __restrict__ offs_t,
                      int* __restrict__ bsum_e, int* __restrict__ bsum_t) {
    int* offs = blockIdx.y ? offs_t : offs_e;
    int* bsum = blockIdx.y ? bsum_t : bsum_e;
    __shared__ int s[256];
    int i = blockIdx.x * 256 + threadIdx.x;
    int x = (i < NSCAN) ? offs[i] : 0;
    s[threadIdx.x] = x;
    __syncthreads();
    #pragma unroll
    for (int off = 1; off < 256; off <<= 1) {
        int v = (threadIdx.x >= off) ? s[threadIdx.x - off] : 0;
        __syncthreads();
        s[threadIdx.x] += v;
        __syncthreads();
    }
    if (i < NSCAN) offs[i] = s[threadIdx.x];
    if (threadIdx.x == 255) bsum[blockIdx.x] = s[255];
}

__global__ void scan2(int* __restrict__ bsum_e, int* __restrict__ bsum_t) {
    int* bsum = blockIdx.y ? bsum_t : bsum_e;
    __shared__ int s[512];
    int i = threadIdx.x;
    s[i] = (i < SCAN_BLOCKS) ? bsum[i] : 0;
    __syncthreads();
    #pragma unroll
    for (int off = 1; off < 512; off <<= 1) {
        int v = (i >= off) ? s[i - off] : 0;
        __syncthreads();
        s[i] += v;
        __syncthreads();
    }
    if (i < SCAN_BLOCKS) bsum[i] = s[i];
}

__global__ void scan3(int* __restrict__ offs_e, int* __restrict__ offs_t,
                      const int* __restrict__ bsum_e, const int* __restrict__ bsum_t,
                      int* __restrict__ cur_e, int* __restrict__ cur_t) {
    int* offs = blockIdx.y ? offs_t : offs_e;
    const int* bsum = blockIdx.y ? bsum_t : bsum_e;
    int* cur = blockIdx.y ? cur_t : cur_e;
    int i = blockIdx.x * 256 + threadIdx.x;
    if (i >= NSCAN) return;
    int v = offs[i] + (blockIdx.x ? bsum[blockIdx.x - 1] : 0);
    offs[i] = v;
    if (i < NN) cur[i] = v;
}

// ---- pass 2: scatter col indices into CSR slots ----
__global__ void scatter_edges(const int* __restrict__ er, const int* __restrict__ ec,
                              const int* __restrict__ tr, const int* __restrict__ tc,
                              int* __restrict__ cur_e, int* __restrict__ cur_t,
                              int* __restrict__ se, int* __restrict__ st) {
    int e = blockIdx.x * 256 + threadIdx.x;
    if (e >= NEDGE) return;
    int p = atomicAdd(&cur_e[er[e]], 1);
    se[p] = ec[e];
    int q = atomicAdd(&cur_t[tr[e]], 1);
    st[q] = tc[e];
}

// ---- gather-aggregate (bf16 tables) + fused X build ----
// one wave per node; half-wave per edge (32 lanes x bf16x4 = 256B row), 2x unroll
__global__ __launch_bounds__(256) void aggregate2(const float* __restrict__ news,
                                                  const __bf16* __restrict__ entb,
                                                  const __bf16* __restrict__ topb,
                                                  const int* __restrict__ offs_e,
                                                  const int* __restrict__ offs_t,
                                                  const int* __restrict__ se,
                                                  const int* __restrict__ st,
                                                  __bf16* __restrict__ X) {
    const int wave = threadIdx.x >> 6, lane = threadIdx.x & 63;
    const int node = blockIdx.x * 4 + wave;
    if (node >= NN) return;
    const int h = lane >> 5;        // edge parity handled by this half
    const int d = (lane & 31) * 4;  // dim group

    float e0 = 0.f, e1 = 0.f, e2 = 0.f, e3 = 0.f;
    float p0 = 0.f, p1 = 0.f, p2 = 0.f, p3 = 0.f;

    const int s0 = offs_e[node], s1 = offs_e[node + 1];
    int i = s0 + h;
    for (; i + 2 < s1; i += 4) {
        int c0 = se[i], c1 = se[i + 2];
        bf16x4 v0 = *(const bf16x4*)(entb + (long)c0 * DD + d);
        bf16x4 v1 = *(const bf16x4*)(entb + (long)c1 * DD + d);
        e0 += (float)v0[0] + (float)v1[0];
        e1 += (float)v0[1] + (float)v1[1];
        e2 += (float)v0[2] + (float)v1[2];
        e3 += (float)v0[3] + (float)v1[3];
    }
    if (i < s1) {
        bf16x4 v = *(const bf16x4*)(entb + (long)se[i] * DD + d);
        e0 += (float)v[0]; e1 += (float)v[1]; e2 += (float)v[2]; e3 += (float)v[3];
    }

    const int t0 = offs_t[node], t1 = offs_t[node + 1];
    i = t0 + h;
    for (; i + 2 < t1; i += 4) {
        int c0 = st[i], c1 = st[i + 2];
        bf16x4 v0 = *(const bf16x4*)(topb + (long)c0 * DD + d);
        bf16x4 v1 = *(const bf16x4*)(topb + (long)c1 * DD + d);
        p0 += (float)v0[0] + (float)v1[0];
        p1 += (float)v0[1] + (float)v1[1];
        p2 += (float)v0[2] + (float)v1[2];
        p3 += (float)v0[3] + (float)v1[3];
    }
    if (i < t1) {
        bf16x4 v = *(const bf16x4*)(topb + (long)st[i] * DD + d);
        p0 += (float)v[0]; p1 += (float)v[1]; p2 += (float)v[2]; p3 += (float)v[3];
    }

    // merge the two halves (xor 32 swaps half-waves)
    e0 += __shfl_xor(e0, 32, 64); e1 += __shfl_xor(e1, 32, 64);
    e2 += __shfl_xor(e2, 32, 64); e3 += __shfl_xor(e3, 32, 64);
    p0 += __shfl_xor(p0, 32, 64); p1 += __shfl_xor(p1, 32, 64);
    p2 += __shfl_xor(p2, 32, 64); p3 += __shfl_xor(p3, 32, 64);

    const float ie = 1.0f / ((float)(s1 - s0) + 1e-8f);
    const float it = 1.0f / ((float)(t1 - t0) + 1e-8f);
    __bf16* xr = X + (long)node * K1;
    if (h == 0) {
        float4 nv = *(const float4*)(news + (long)node * DD + d);
        *(bf16x4*)(xr + d)      = bf16x4{f2b(nv.x), f2b(nv.y), f2b(nv.z), f2b(nv.w)};
        *(bf16x4*)(xr + DD + d) = bf16x4{f2b(e0 * ie), f2b(e1 * ie), f2b(e2 * ie), f2b(e3 * ie)};
    } else {
        *(bf16x4*)(xr + 2*DD + d) = bf16x4{f2b(p0 * it), f2b(p1 * it), f2b(p2 * it), f2b(p3 * it)};
    }
}

// ---- W1 [384,512] -> W1T bf16 [512,384]; W2 [512,128] -> W2T bf16 [128,512] ----
__global__ void conv_w(const float* __restrict__ W1, const float* __restrict__ W2,
                       __bf16* __restrict__ W1T, __bf16* __restrict__ W2T) {
    int i = blockIdx.x * 256 + threadIdx.x;
    if (i < K1 * HID) {
        int k = i / HID, n = i % HID;
        W1T[n * K1 + k] = f2b(W1[i]);
    } else {
        int j = i - K1 * HID;
        if (j < HID * OUTD) {
            int k = j / OUTD, n = j % OUTD;
            W2T[n * HID + k] = f2b(W2[j]);
        }
    }
}

// ---- m97-style 128x128 GEMM: C[M,N] = act(A[M,K] @ BT[N,K]^T + bias) ----
// 256 threads = 4 waves; wave w computes 64x64 quadrant (wm=w>>1, wn=w&1).
// BK=32, LDS row-major [row][32] (64B rows), staged via global_load_lds x16B.
template<int TANH>
__global__ __launch_bounds__(256) void gemm128(const __bf16* __restrict__ A,
                                               const __bf16* __restrict__ BT,
                                               const float* __restrict__ bias,
                                               void* __restrict__ Cout,
                                               int M, int N, int K) {
    __shared__ __bf16 As[128 * 32];
    __shared__ __bf16 Bs[128 * 32];
    const int bm = blockIdx.x * 128;
    const int bn = blockIdx.y * 128;
    const int t = threadIdx.x;
    const int lane = t & 63;
    const int w = t >> 6;
    const int quad = lane >> 4;
    const int l16 = lane & 15;
    const int wm = w >> 1, wn = w & 1;

    // staging geometry: round r covers rows r*64 + w*16 + (lane>>2), k-chunk (lane&3)*8
    const int srow = w * 16 + (lane >> 2);
    const int skk = (lane & 3) * 8;

    f32x4 acc[4][4];
    #pragma unroll
    for (int i = 0; i < 4; i++)
        #pragma unroll
        for (int j = 0; j < 4; j++)
            #pragma unroll
            for (int r = 0; r < 4; r++) acc[i][j][r] = 0.0f;

    // A row clamp (garbage rows beyond M only corrupt discarded C rows)
    int ar0 = bm + srow;        if (ar0 >= M) ar0 = M - 1;
    int ar1 = bm + srow + 64;   if (ar1 >= M) ar1 = M - 1;
    const int br0 = bn + srow;
    const int br1 = bn + srow + 64;

    const int nk = K >> 5;
    for (int kt = 0; kt < nk; kt++) {
        const int k0 = kt << 5;
        __syncthreads();
        gll16(A  + (long)ar0 * K + k0 + skk, (void*)(As + w * 512));
        gll16(A  + (long)ar1 * K + k0 + skk, (void*)(As + 2048 + w * 512));
        gll16(BT + (long)br0 * K + k0 + skk, (void*)(Bs + w * 512));
        gll16(BT + (long)br1 * K + k0 + skk, (void*)(Bs + 2048 + w * 512));
        __syncthreads();
        bf16x8 af[4], bfr[4];
        #pragma unroll
        for (int i = 0; i < 4; i++) {
            af[i]  = *(const bf16x8*)&As[(wm * 64 + i * 16 + l16) * 32 + quad * 8];
            bfr[i] = *(const bf16x8*)&Bs[(wn * 64 + i * 16 + l16) * 32 + quad * 8];
        }
        #pragma unroll
        for (int i = 0; i < 4; i++)
            #pragma unroll
            for (int j = 0; j < 4; j++)
                acc[i][j] = __builtin_amdgcn_mfma_f32_16x16x32_bf16(af[i], bfr[j], acc[i][j], 0, 0, 0);
    }

    // epilogue: C/D layout col=l16, row=quad*4+r within each 16x16 subtile
    #pragma unroll
    for (int j = 0; j < 4; j++) {
        const int gc = bn + wn * 64 + j * 16 + l16;
        const float bb = bias[gc];
        #pragma unroll
        for (int i = 0; i < 4; i++) {
            const int rbase = bm + wm * 64 + i * 16 + quad * 4;
            #pragma unroll
            for (int r = 0; r < 4; r++) {
                const int gr = rbase + r;
                if (gr < M) {
                    float v = acc[i][j][r] + bb;
                    if (TANH) {
                        ((__bf16*)Cout)[(long)gr * N + gc] = f2b(ftanh(v));
                    } else {
                        ((float*)Cout)[(long)gr * N + gc] = v;
                    }
                }
            }
        }
    }
}

extern "C" void kernel_launch(void* const* d_in, const int* in_sizes, int n_in,
                              void* d_out, int out_size, void* d_ws, size_t ws_size,
                              hipStream_t stream) {
    const float* news  = (const float*)d_in[0];
    const float* ent_f = (const float*)d_in[1];
    const float* top_f = (const float*)d_in[2];
    const int* ent_row = (const int*)d_in[3];
    const int* ent_col = (const int*)d_in[4];
    const int* top_row = (const int*)d_in[5];
    const int* top_col = (const int*)d_in[6];
    const float* W1 = (const float*)d_in[7];
    const float* b1 = (const float*)d_in[8];
    const float* W2 = (const float*)d_in[9];
    const float* b2 = (const float*)d_in[10];

    char* ws = (char*)d_ws;
    // layout (bytes) — region [0, 27716160) is dead after `aggregate2`, aliased by H:
    //   [0,         400016)   offs_e int[100001]
    //   [400016,    800032)   offs_t int[100001]
    //   [800032,   1200032)   cur_e  int[100000]
    //   [1200032,  1600032)   cur_t  int[100000]
    //   [1600032,  1602080)   bsum_e int[512]
    //   [1602080,  1604128)   bsum_t int[512]
    //   [1604160,  8004160)   se     int[1.6M]
    //   [8004160, 14404160)   st     int[1.6M]
    //   [14404160, 27204160)  entb bf16 [50000*128]
    //   [27204160, 27716160)  topb bf16 [2000*128]
    //   [0,        102400000) H bf16 [100000*512]  (after aggregate2)
    //   [102400000,179200000) X bf16 [100000*384]
    //   [179200000,179593216) W1T bf16 [512*384]
    //   [179593216,179724288) W2T bf16 [128*512]
    int* offs_e = (int*)(ws + 0);
    int* offs_t = (int*)(ws + 400016);
    int* cur_e  = (int*)(ws + 800032);
    int* cur_t  = (int*)(ws + 1200032);
    int* bsum_e = (int*)(ws + 1600032);
    int* bsum_t = (int*)(ws + 1602080);
    int* se     = (int*)(ws + 1604160);
    int* st     = (int*)(ws + 8004160);
    __bf16* entb = (__bf16*)(ws + 14404160);
    __bf16* topb = (__bf16*)(ws + 27204160);
    __bf16* H   = (__bf16*)(ws + 0);
    __bf16* X   = (__bf16*)(ws + 102400000);
    __bf16* W1T = (__bf16*)(ws + 179200000);
    __bf16* W2T = (__bf16*)(ws + 179593216);

    hipMemsetAsync(ws, 0, 800032, stream);   // zero offs_e/offs_t only
    conv_w<<<1024, 256, 0, stream>>>(W1, W2, W1T, W2T);
    conv_feats<<<6500, 256, 0, stream>>>(ent_f, top_f, entb, topb);
    count_edges<<<NEDGE / 256, 256, 0, stream>>>(ent_row, top_row, offs_e, offs_t);
    scan1<<<dim3(SCAN_BLOCKS, 2), 256, 0, stream>>>(offs_e, offs_t, bsum_e, bsum_t);
    scan2<<<dim3(1, 2), 512, 0, stream>>>(bsum_e, bsum_t);
    scan3<<<dim3(SCAN_BLOCKS, 2), 256, 0, stream>>>(offs_e, offs_t, bsum_e, bsum_t, cur_e, cur_t);
    scatter_edges<<<NEDGE / 256, 256, 0, stream>>>(ent_row, ent_col, top_row, top_col,
                                                   cur_e, cur_t, se, st);
    aggregate2<<<NN / 4, 256, 0, stream>>>(news, entb, topb, offs_e, offs_t, se, st, X);
    gemm128<1><<<dim3(782, 4), 256, 0, stream>>>(X, W1T, b1, (void*)H, NN, HID, K1);
    gemm128<0><<<dim3(782, 1), 256, 0, stream>>>(H, W2T, b2, d_out, NN, OUTD, HID);
}